// Round 3
// baseline (663.654 us; speedup 1.0000x reference)
//
#include <hip/hip_runtime.h>
#include <hip/hip_bf16.h>
#include <cstdint>

#define NN 8192
#define F 512
#define LOG2E 1.4426950408889634f

typedef __attribute__((ext_vector_type(8))) short bf16x8;
typedef __attribute__((ext_vector_type(4))) float f32x4;
typedef unsigned int uint32;
typedef unsigned long long u64;

__device__ __forceinline__ short f2bf(float x){
  __hip_bfloat16 h = __float2bfloat16(x);
  return *reinterpret_cast<short*>(&h);
}

// ---------- wa = W @ a1 / W @ a2 : one wave per output element ----------
__global__ __launch_bounds__(256) void k_wa(const float* __restrict__ W, const float* __restrict__ attn,
                     float* __restrict__ wa){
  const int lane = threadIdx.x&63, wid = threadIdx.x>>6;
  const int id = blockIdx.x*4 + wid;       // 0..1023 : b = id>>9, c = id&511
  const int b = id>>9, c = id&511;
  const float4* Wr = (const float4*)(W + (size_t)c*F);
  const float4* av = (const float4*)(attn + b*F);
  float s = 0.f;
  #pragma unroll
  for (int h=0;h<2;++h){
    const int k = lane + h*64;
    const float4 wv = Wr[k], a = av[k];
    s += wv.x*a.x + wv.y*a.y + wv.z*a.z + wv.w*a.w;
  }
  for (int off=32;off;off>>=1) s += __shfl_down(s,off);
  if (lane==0) wa[id] = s;
}

// ---------- W^T -> bf16 via LDS tile ----------
__global__ __launch_bounds__(256) void k_tw(const float* __restrict__ W, short* __restrict__ WbT){
  __shared__ short t[64][72];
  const int k0 = blockIdx.x*64, n0 = blockIdx.y*64;
  #pragma unroll
  for (int it=0;it<16;++it){
    const int idx = it*256 + threadIdx.x;
    const int r = idx>>6, c = idx&63;
    t[r][c] = f2bf(W[(size_t)(k0+r)*F + n0 + c]);
  }
  __syncthreads();
  #pragma unroll
  for (int it=0;it<2;++it){
    const int idx = it*256 + threadIdx.x;
    const int n = idx>>3, g = idx&7;
    short v[8];
    #pragma unroll
    for (int e=0;e<8;++e) v[e] = t[g*8+e][n];
    *(uint4*)(WbT + (size_t)(n0+n)*F + k0 + g*8) = *(const uint4*)v;
  }
}

// ---------- fused: s1L + u/w tables + X->bf16 ; one wave per row ----------
__global__ __launch_bounds__(256) void k_prep(const float* __restrict__ X, const float* __restrict__ wa,
    short* __restrict__ Xb, float* __restrict__ s1L, float2* __restrict__ uwf, uint32* __restrict__ uwb){
  const int lane = threadIdx.x&63, wid = threadIdx.x>>6;
  const int row = blockIdx.x*4 + wid;
  const float4* X4 = (const float4*)(X + (size_t)row*F);
  const float4* A4 = (const float4*)wa;
  const float4* B4 = (const float4*)(wa + F);
  uint2* Xb4 = (uint2*)(Xb + (size_t)row*F);
  float a1 = 0.f, a2 = 0.f;
  #pragma unroll
  for (int h=0;h<2;++h){
    const int c = lane + h*64;
    const float4 x = X4[c];
    const float4 a = A4[c];
    const float4 b = B4[c];
    a1 += x.x*a.x + x.y*a.y + x.z*a.z + x.w*a.w;
    a2 += x.x*b.x + x.y*b.y + x.z*b.z + x.w*b.w;
    short o[4] = {f2bf(x.x),f2bf(x.y),f2bf(x.z),f2bf(x.w)};
    Xb4[c] = *(const uint2*)o;
  }
  for (int off=32;off;off>>=1){ a1 += __shfl_down(a1,off); a2 += __shfl_down(a2,off); }
  if (lane==0){
    const float s1 = a1*LOG2E, s2 = a2*LOG2E;
    s1L[row] = s1;
    const float u = exp2f(s2), w = exp2f(0.2f*s2);
    uwf[row] = make_float2(u, w);
    uwb[row] = (uint32)(unsigned short)f2bf(u) | ((uint32)(unsigned short)f2bf(w)<<16);
  }
}

// ---------- GEMM1: h = Xb @ WbT^T, writes HT[feature][node] bf16 ----------
__global__ __launch_bounds__(256,2) void k_gemm1(const short* __restrict__ Xb,
    const short* __restrict__ WbT, short* __restrict__ HT){
  __shared__ char smem[33280];
  short* At = (short*)smem;
  short* Bt = (short*)(smem + 16384);
  const int tid=threadIdx.x, lane=tid&63, wid=tid>>6;
  const int m0 = blockIdx.x*128, n0 = blockIdx.y*128;
  f32x4 acc[2][8];
  #pragma unroll
  for (int a=0;a<2;++a)
    #pragma unroll
    for (int b=0;b<8;++b) acc[a][b] = (f32x4){0.f,0.f,0.f,0.f};

  for (int t=0;t<8;++t){
    const int k0 = t*64;
    __syncthreads();
    #pragma unroll
    for (int rnd=0;rnd<4;++rnd){
      const int s = rnd*256 + tid;
      const int n = s>>3, kc = s&7;
      uint4 va = *(const uint4*)(Xb  + (size_t)(m0+n)*F + k0 + kc*8);
      uint4 vb = *(const uint4*)(WbT + (size_t)(n0+n)*F + k0 + kc*8);
      const int off = n*128 + ((kc^(n&7))*16);
      *(uint4*)((char*)At + off) = va;
      *(uint4*)((char*)Bt + off) = vb;
    }
    __syncthreads();
    #pragma unroll
    for (int ks=0;ks<2;++ks){
      const int kc = ks*4 + (lane>>4);
      int r0 = wid*32 + (lane&15);
      int r1 = r0 + 16;
      bf16x8 af0 = *(const bf16x8*)((char*)At + r0*128 + ((kc^(r0&7))*16));
      bf16x8 af1 = *(const bf16x8*)((char*)At + r1*128 + ((kc^(r1&7))*16));
      #pragma unroll
      for (int nf=0;nf<8;++nf){
        const int c = nf*16 + (lane&15);
        bf16x8 bf = *(const bf16x8*)((char*)Bt + c*128 + ((kc^(c&7))*16));
        acc[0][nf] = __builtin_amdgcn_mfma_f32_16x16x32_bf16(af0, bf, acc[0][nf],0,0,0);
        acc[1][nf] = __builtin_amdgcn_mfma_f32_16x16x32_bf16(af1, bf, acc[1][nf],0,0,0);
      }
    }
  }
  __syncthreads();
  short* ct = (short*)smem;                 // [128][130] bf16
  #pragma unroll
  for (int mf=0;mf<2;++mf)
    #pragma unroll
    for (int nf=0;nf<8;++nf)
      #pragma unroll
      for (int q=0;q<4;++q){
        int r = wid*32 + mf*16 + (lane>>4)*4 + q;
        int c = nf*16 + (lane&15);
        ct[r*130+c] = f2bf(acc[mf][nf][q]);
      }
  __syncthreads();
  {
    const int c = tid>>1, ih0 = (tid&1)*64;
    #pragma unroll
    for (int i8=0;i8<8;++i8){
      short v[8];
      #pragma unroll
      for (int e=0;e<8;++e) v[e] = ct[(ih0+i8*8+e)*130 + c];
      *(uint4*)(HT + (size_t)(n0+c)*NN + m0 + ih0 + i8*8) = *(const uint4*)v;
    }
  }
}

// ---------- stats: single pass, contiguous int4 loads, no transcendentals ----------
__global__ __launch_bounds__(256) void k_stats(const int* __restrict__ adj,
    const float* __restrict__ s1L, const float* __restrict__ uwf,
    uint32* __restrict__ bm32, float2* __restrict__ rowE2){
  __shared__ unsigned char nib[2048];
  __shared__ float zred[4];
  const int tid=threadIdx.x, lane=tid&63, wid=tid>>6;
  const int row = blockIdx.x;
  const float s1 = s1L[row];
  const float A0 = exp2f(s1), B0 = exp2f(0.2f*s1);
  const int4* a4 = (const int4*)(adj + (size_t)row*NN);
  const float4* uw4 = (const float4*)uwf;
  float z = 0.f;
  #pragma unroll
  for (int it=0;it<8;++it){
    const int c4 = it*256 + tid;           // covers cols 4*c4 .. 4*c4+3
    const int4 a = a4[c4];
    const float4 p0 = uw4[c4*2];
    const float4 p1 = uw4[c4*2+1];
    const float t0 = fmaxf(A0*p0.x, B0*p0.y);
    const float t1 = fmaxf(A0*p0.z, B0*p0.w);
    const float t2 = fmaxf(A0*p1.x, B0*p1.y);
    const float t3 = fmaxf(A0*p1.z, B0*p1.w);
    const int b0 = a.x>0, b1 = a.y>0, b2 = a.z>0, b3 = a.w>0;
    z += b0 ? t0 : 0.f;
    z += b1 ? t1 : 0.f;
    z += b2 ? t2 : 0.f;
    z += b3 ? t3 : 0.f;
    nib[c4] = (unsigned char)(b0 | (b1<<1) | (b2<<2) | (b3<<3));
  }
  for (int off=32;off;off>>=1) z += __shfl_down(z,off);
  if (lane==0) zred[wid] = z;
  __syncthreads();
  {
    const u64 nv = *(const u64*)&nib[tid*8];
    uint32 m = 0;
    #pragma unroll
    for (int i=0;i<8;++i) m |= ((uint32)((nv>>(8*i)) & 0xFull)) << (4*i);
    bm32[(size_t)row*256 + tid] = m;       // word tid = cols 32*tid .. +31
  }
  if (tid==0){
    const float Z = zred[0]+zred[1]+zred[2]+zred[3];
    const float inv = 1.f/Z;
    rowE2[row] = make_float2(A0*inv, B0*inv);
  }
}

// ---------- PV: out = elu( softmax-weights @ H ), 64x256 block, 4 waves 4x4-frag ----------
__global__ __launch_bounds__(256,3) void k_pv(const short* __restrict__ HT,
    const unsigned char* __restrict__ bm8, const float2* __restrict__ rowE2,
    const uint32* __restrict__ uwb, float* __restrict__ out){
  __shared__ short At[64*64];     // 8KB, XOR-swizzled A tile (generated)
  __shared__ short Btm[256*64];   // 32KB, XOR-swizzled B tile (staged)
  const int tid=threadIdx.x, lane=tid&63, wid=tid>>6;
  const int m0 = blockIdx.x*64, n0 = blockIdx.y*256;

  // ---- B staging: wave wid covers linear slots [wid*512, wid*512+512), 8 x b128 per wave.
  // linear slot s holds data for kc = (s&7)^(n&7): pre-swizzled source, linear dest.
  // n = wid*64 + (lane>>3) + i*8 ; kc = (lane&7)^((lane>>3)&7)  (i-independent)
  const int bn0 = wid*64 + (lane>>3);
  const int bkc = (lane&7) ^ ((lane>>3)&7);
  const int boff0 = (n0 + bn0)*NN + bkc*8;       // element offset; + i*8*NN + k0
  char* Bdst = (char*)Btm + (wid*512 + lane)*16; // + i*1024

  // ---- A-gen: rounds r=0,1: row n = r*32 + (tid>>3), kchunk akc = tid&7
  const int an = tid>>3, akc = tid&7;
  float EA0, EB0, EA1, EB1;
  { float2 E = rowE2[m0 + an];      EA0 = E.x; EB0 = E.y; }
  { float2 E = rowE2[m0 + 32 + an]; EA1 = E.x; EB1 = E.y; }
  const unsigned char* bmp0 = bm8 + (size_t)(m0 + an)*1024 + akc;
  const unsigned char* bmp1 = bmp0 + 32*1024;
  const uint32* uwp = uwb + akc*8;
  int adst0, adst1;
  { const int n = an;      adst0 = n*128 + ((akc^(n&7))*16); }
  { const int n = 32 + an; adst1 = n*128 + ((akc^(n&7))*16); }

  f32x4 acc[4][4];
  #pragma unroll
  for (int i=0;i<4;++i)
    #pragma unroll
    for (int j=0;j<4;++j) acc[i][j] = (f32x4){0.f,0.f,0.f,0.f};

  // prefetch t=0 inputs
  uint4 gb[8];
  #pragma unroll
  for (int i=0;i<8;++i) gb[i] = *(const uint4*)(HT + boff0 + i*(8*NN));
  uint4 uq0 = *(const uint4*)(uwp);
  uint4 uq1 = *(const uint4*)(uwp + 4);
  uint32 ab0 = bmp0[0], ab1 = bmp1[0];

  for (int t=0;t<128;++t){
    // ---- stage B regs -> LDS
    #pragma unroll
    for (int i=0;i<8;++i) *(uint4*)(Bdst + i*1024) = gb[i];
    // ---- A-gen -> LDS (weights for this block's 64 rows x this K-slice)
    {
      float uu[8], ww[8];
      const uint32 qa[8] = {uq0.x,uq0.y,uq0.z,uq0.w,uq1.x,uq1.y,uq1.z,uq1.w};
      #pragma unroll
      for (int e=0;e<8;++e){
        uu[e] = __uint_as_float(qa[e]<<16);
        ww[e] = __uint_as_float(qa[e]&0xffff0000u);
      }
      short av0[8], av1[8];
      #pragma unroll
      for (int e=0;e<8;++e){
        float v0 = fmaxf(EA0*uu[e], EB0*ww[e]);
        float v1 = fmaxf(EA1*uu[e], EB1*ww[e]);
        av0[e] = f2bf(((ab0>>e)&1u) ? v0 : 0.0f);
        av1[e] = f2bf(((ab1>>e)&1u) ? v1 : 0.0f);
      }
      *(uint4*)((char*)At + adst0) = *(const uint4*)av0;
      *(uint4*)((char*)At + adst1) = *(const uint4*)av1;
    }
    __syncthreads();
    // ---- prefetch t+1
    if (t < 127){
      const int k1 = (t+1)*64;
      #pragma unroll
      for (int i=0;i<8;++i) gb[i] = *(const uint4*)(HT + boff0 + i*(8*NN) + k1);
      uq0 = *(const uint4*)(uwp + k1);
      uq1 = *(const uint4*)(uwp + k1 + 4);
      ab0 = bmp0[(t+1)*8];
      ab1 = bmp1[(t+1)*8];
    }
    // ---- MFMA: 4x4 fragments per wave
    #pragma unroll
    for (int ks=0;ks<2;++ks){
      const int kc = ks*4 + (lane>>4);
      bf16x8 af[4];
      #pragma unroll
      for (int mf=0;mf<4;++mf){
        const int rr = mf*16 + (lane&15);
        af[mf] = *(const bf16x8*)((char*)At + rr*128 + ((kc^(rr&7))*16));
      }
      #pragma unroll
      for (int nf=0;nf<4;++nf){
        const int c = wid*64 + nf*16 + (lane&15);
        bf16x8 bv = *(const bf16x8*)((char*)Btm + c*128 + ((kc^(c&7))*16));
        #pragma unroll
        for (int mf=0;mf<4;++mf)
          acc[mf][nf] = __builtin_amdgcn_mfma_f32_16x16x32_bf16(af[mf], bv, acc[mf][nf],0,0,0);
      }
    }
    __syncthreads();
  }
  // ---- epilogue: ELU + store
  #pragma unroll
  for (int mf=0;mf<4;++mf)
    #pragma unroll
    for (int nf=0;nf<4;++nf){
      const int col = n0 + wid*64 + nf*16 + (lane&15);
      #pragma unroll
      for (int q=0;q<4;++q){
        const int r = m0 + mf*16 + (lane>>4)*4 + q;
        const float x = acc[mf][nf][q];
        out[(size_t)r*F + col] = (x > 0.f) ? x : expm1f(x);
      }
    }
}

extern "C" void kernel_launch(void* const* d_in, const int* in_sizes, int n_in,
                              void* d_out, int out_size, void* d_ws, size_t ws_size,
                              hipStream_t stream) {
  (void)in_sizes; (void)n_in; (void)out_size; (void)ws_size;
  const int*   adj  = (const int*)d_in[0];
  const float* X    = (const float*)d_in[1];
  const float* W    = (const float*)d_in[2];
  const float* attn = (const float*)d_in[3];
  float* out = (float*)d_out;
  char* ws = (char*)d_ws;
  short*  HT   = (short*)(ws);                      // 8 MB
  short*  Xb   = (short*)(ws + 8388608);            // 8 MB
  short*  WbT  = (short*)(ws + 16777216);           // 0.5 MB
  uint32* bm32 = (uint32*)(ws + 17301504);          // 8 MB
  float*  s1L  = (float*)(ws + 25690112);           // 32 KB
  float*  uwf  = (float*)(ws + 25722880);           // 64 KB (float2)
  uint32* uwb  = (uint32*)(ws + 25788416);          // 32 KB
  float2* rowE2= (float2*)(ws + 25821184);          // 64 KB
  float*  wa   = (float*)(ws + 25886720);           // 4 KB

  k_wa   <<<dim3(256),   dim3(256), 0, stream>>>(W, attn, wa);
  k_tw   <<<dim3(8,8),   dim3(256), 0, stream>>>(W, WbT);
  k_prep <<<dim3(2048),  dim3(256), 0, stream>>>(X, wa, Xb, s1L, (float2*)uwf, uwb);
  k_gemm1<<<dim3(64,4),  dim3(256), 0, stream>>>(Xb, WbT, HT);
  k_stats<<<dim3(8192),  dim3(256), 0, stream>>>(adj, s1L, uwf, bm32, rowE2);
  k_pv   <<<dim3(128,2), dim3(256), 0, stream>>>(HT, (const unsigned char*)bm32, rowE2, uwb, out);
}

// Round 4
// 220.988 us; speedup vs baseline: 3.0031x; 3.0031x over previous
//
#include <hip/hip_runtime.h>
#include <hip/hip_bf16.h>
#include <cstdint>

#define NN 8192
#define F 512
#define LOG2E 1.4426950408889634f

typedef __attribute__((ext_vector_type(8))) short bf16x8;
typedef __attribute__((ext_vector_type(4))) float f32x4;
typedef unsigned int uint32;
typedef unsigned long long u64;
typedef unsigned char uchar;

#define AS1 __attribute__((address_space(1)))
#define AS3 __attribute__((address_space(3)))
__device__ __forceinline__ void gload16(const void* g, void* l){
  __builtin_amdgcn_global_load_lds((const AS1 uint32*)g, (AS3 uint32*)l, 16, 0, 0);
}

__device__ __forceinline__ short f2bf(float x){
  __hip_bfloat16 h = __float2bfloat16(x);
  return *reinterpret_cast<short*>(&h);
}

// ---------- wa = W @ a1 / W @ a2 ----------
__global__ __launch_bounds__(256) void k_wa(const float* __restrict__ W, const float* __restrict__ attn,
                     float* __restrict__ wa){
  const int lane = threadIdx.x&63, wid = threadIdx.x>>6;
  const int id = blockIdx.x*4 + wid;
  const int b = id>>9, c = id&511;
  const float4* Wr = (const float4*)(W + (size_t)c*F);
  const float4* av = (const float4*)(attn + b*F);
  float s = 0.f;
  #pragma unroll
  for (int h=0;h<2;++h){
    const int k = lane + h*64;
    const float4 wv = Wr[k], a = av[k];
    s += wv.x*a.x + wv.y*a.y + wv.z*a.z + wv.w*a.w;
  }
  for (int off=32;off;off>>=1) s += __shfl_down(s,off);
  if (lane==0) wa[id] = s;
}

// ---------- W^T -> bf16 via LDS tile ----------
__global__ __launch_bounds__(256) void k_tw(const float* __restrict__ W, short* __restrict__ WbT){
  __shared__ short t[64][72];
  const int k0 = blockIdx.x*64, n0 = blockIdx.y*64;
  #pragma unroll
  for (int it=0;it<16;++it){
    const int idx = it*256 + threadIdx.x;
    const int r = idx>>6, c = idx&63;
    t[r][c] = f2bf(W[(size_t)(k0+r)*F + n0 + c]);
  }
  __syncthreads();
  #pragma unroll
  for (int it=0;it<2;++it){
    const int idx = it*256 + threadIdx.x;
    const int n = idx>>3, g = idx&7;
    short v[8];
    #pragma unroll
    for (int e=0;e<8;++e) v[e] = t[g*8+e][n];
    *(uint4*)(WbT + (size_t)(n0+n)*F + k0 + g*8) = *(const uint4*)v;
  }
}

// ---------- fused: s1L + u/w tables + X->bf16 ----------
__global__ __launch_bounds__(256) void k_prep(const float* __restrict__ X, const float* __restrict__ wa,
    short* __restrict__ Xb, float* __restrict__ s1L, float2* __restrict__ uwf, uint32* __restrict__ uwb){
  const int lane = threadIdx.x&63, wid = threadIdx.x>>6;
  const int row = blockIdx.x*4 + wid;
  const float4* X4 = (const float4*)(X + (size_t)row*F);
  const float4* A4 = (const float4*)wa;
  const float4* B4 = (const float4*)(wa + F);
  uint2* Xb4 = (uint2*)(Xb + (size_t)row*F);
  float a1 = 0.f, a2 = 0.f;
  #pragma unroll
  for (int h=0;h<2;++h){
    const int c = lane + h*64;
    const float4 x = X4[c];
    const float4 a = A4[c];
    const float4 b = B4[c];
    a1 += x.x*a.x + x.y*a.y + x.z*a.z + x.w*a.w;
    a2 += x.x*b.x + x.y*b.y + x.z*b.z + x.w*b.w;
    short o[4] = {f2bf(x.x),f2bf(x.y),f2bf(x.z),f2bf(x.w)};
    Xb4[c] = *(const uint2*)o;
  }
  for (int off=32;off;off>>=1){ a1 += __shfl_down(a1,off); a2 += __shfl_down(a2,off); }
  if (lane==0){
    const float s1 = a1*LOG2E, s2 = a2*LOG2E;
    s1L[row] = s1;
    const float u = exp2f(s2), w = exp2f(0.2f*s2);
    uwf[row] = make_float2(u, w);
    uwb[row] = (uint32)(unsigned short)f2bf(u) | ((uint32)(unsigned short)f2bf(w)<<16);
  }
}

// ---------- GEMM1: h = Xb @ WbT^T, writes HT[feature][node] bf16 ----------
__global__ __launch_bounds__(256,2) void k_gemm1(const short* __restrict__ Xb,
    const short* __restrict__ WbT, short* __restrict__ HT){
  __shared__ char smem[33280];
  short* At = (short*)smem;
  short* Bt = (short*)(smem + 16384);
  const int tid=threadIdx.x, lane=tid&63, wid=tid>>6;
  const int m0 = blockIdx.x*128, n0 = blockIdx.y*128;
  f32x4 acc[2][8];
  #pragma unroll
  for (int a=0;a<2;++a)
    #pragma unroll
    for (int b=0;b<8;++b) acc[a][b] = (f32x4){0.f,0.f,0.f,0.f};

  for (int t=0;t<8;++t){
    const int k0 = t*64;
    __syncthreads();
    #pragma unroll
    for (int rnd=0;rnd<4;++rnd){
      const int s = rnd*256 + tid;
      const int n = s>>3, kc = s&7;
      uint4 va = *(const uint4*)(Xb  + (size_t)(m0+n)*F + k0 + kc*8);
      uint4 vb = *(const uint4*)(WbT + (size_t)(n0+n)*F + k0 + kc*8);
      const int off = n*128 + ((kc^(n&7))*16);
      *(uint4*)((char*)At + off) = va;
      *(uint4*)((char*)Bt + off) = vb;
    }
    __syncthreads();
    #pragma unroll
    for (int ks=0;ks<2;++ks){
      const int kc = ks*4 + (lane>>4);
      int r0 = wid*32 + (lane&15);
      int r1 = r0 + 16;
      bf16x8 af0 = *(const bf16x8*)((char*)At + r0*128 + ((kc^(r0&7))*16));
      bf16x8 af1 = *(const bf16x8*)((char*)At + r1*128 + ((kc^(r1&7))*16));
      #pragma unroll
      for (int nf=0;nf<8;++nf){
        const int c = nf*16 + (lane&15);
        bf16x8 bf = *(const bf16x8*)((char*)Bt + c*128 + ((kc^(c&7))*16));
        acc[0][nf] = __builtin_amdgcn_mfma_f32_16x16x32_bf16(af0, bf, acc[0][nf],0,0,0);
        acc[1][nf] = __builtin_amdgcn_mfma_f32_16x16x32_bf16(af1, bf, acc[1][nf],0,0,0);
      }
    }
  }
  __syncthreads();
  short* ct = (short*)smem;                 // [128][130] bf16
  #pragma unroll
  for (int mf=0;mf<2;++mf)
    #pragma unroll
    for (int nf=0;nf<8;++nf)
      #pragma unroll
      for (int q=0;q<4;++q){
        int r = wid*32 + mf*16 + (lane>>4)*4 + q;
        int c = nf*16 + (lane&15);
        ct[r*130+c] = f2bf(acc[mf][nf][q]);
      }
  __syncthreads();
  {
    const int c = tid>>1, ih0 = (tid&1)*64;
    #pragma unroll
    for (int i8=0;i8<8;++i8){
      short v[8];
      #pragma unroll
      for (int e=0;e<8;++e) v[e] = ct[(ih0+i8*8+e)*130 + c];
      *(uint4*)(HT + (size_t)(n0+c)*NN + m0 + ih0 + i8*8) = *(const uint4*)v;
    }
  }
}

// ---------- stats: single pass ----------
__global__ __launch_bounds__(256) void k_stats(const int* __restrict__ adj,
    const float* __restrict__ s1L, const float* __restrict__ uwf,
    uint32* __restrict__ bm32, float2* __restrict__ rowE2){
  __shared__ uchar nib[2048];
  __shared__ float zred[4];
  const int tid=threadIdx.x, lane=tid&63, wid=tid>>6;
  const int row = blockIdx.x;
  const float s1 = s1L[row];
  const float A0 = exp2f(s1), B0 = exp2f(0.2f*s1);
  const int4* a4 = (const int4*)(adj + (size_t)row*NN);
  const float4* uw4 = (const float4*)uwf;
  float z = 0.f;
  #pragma unroll
  for (int it=0;it<8;++it){
    const int c4 = it*256 + tid;
    const int4 a = a4[c4];
    const float4 p0 = uw4[c4*2];
    const float4 p1 = uw4[c4*2+1];
    const float t0 = fmaxf(A0*p0.x, B0*p0.y);
    const float t1 = fmaxf(A0*p0.z, B0*p0.w);
    const float t2 = fmaxf(A0*p1.x, B0*p1.y);
    const float t3 = fmaxf(A0*p1.z, B0*p1.w);
    const int b0 = a.x>0, b1 = a.y>0, b2 = a.z>0, b3 = a.w>0;
    z += b0 ? t0 : 0.f;
    z += b1 ? t1 : 0.f;
    z += b2 ? t2 : 0.f;
    z += b3 ? t3 : 0.f;
    nib[c4] = (uchar)(b0 | (b1<<1) | (b2<<2) | (b3<<3));
  }
  for (int off=32;off;off>>=1) z += __shfl_down(z,off);
  if (lane==0) zred[wid] = z;
  __syncthreads();
  {
    const u64 nv = *(const u64*)&nib[tid*8];
    uint32 m = 0;
    #pragma unroll
    for (int i=0;i<8;++i) m |= ((uint32)((nv>>(8*i)) & 0xFull)) << (4*i);
    bm32[(size_t)row*256 + tid] = m;
  }
  if (tid==0){
    const float Z = zred[0]+zred[1]+zred[2]+zred[3];
    const float inv = 1.f/Z;
    rowE2[row] = make_float2(A0*inv, B0*inv);
  }
}

// ---------- PV: split-K partial GEMM. BM=128,BN=128,BK=64, 4 waves of 64x64 ----------
__global__ __launch_bounds__(256,2) void k_pv(const short* __restrict__ HT,
    const uchar* __restrict__ bm8, const float2* __restrict__ rowE2,
    const uint32* __restrict__ uwb, float* __restrict__ P0, float* __restrict__ P1,
    int ksteps){
  __shared__ short At[128*64];    // 16KB swizzled (generated weights)
  __shared__ short Btm[128*64];   // 16KB swizzled (HT panel)
  const int tid=threadIdx.x, lane=tid&63, wid=tid>>6;
  const int m0 = blockIdx.x*128, n0 = blockIdx.y*128;
  const int kz0 = blockIdx.z * (ksteps*64);
  float* outP = blockIdx.z ? P1 : P0;

  // ---- B staging via global_load_lds: linear dest, pre-swizzled per-lane source.
  // round r: slot s = r*256 + wid*64 + lane -> row n = s>>3, kc = (lane&7)^((lane>>3)&7)
  const int bn  = wid*8 + (lane>>3);
  const int bkc = (lane&7) ^ ((lane>>3)&7);
  const short* gB = HT + (size_t)(n0+bn)*NN + kz0 + bkc*8;   // + r*32*NN + k0
  char* ldsB = (char*)Btm + wid*1024;                         // + r*4096 (wave-uniform)

  // ---- A-gen assignment: kc = tid&7, rows = tid>>3 + {0,32,64,96}
  const int akc = tid&7, ar = tid>>3;
  const int axor = ((akc ^ (ar&7))*16);
  float EA[4], EB[4];
  int adst[4];
  const uchar* bmp[4];
  #pragma unroll
  for (int rr=0;rr<4;++rr){
    const int row = ar + rr*32;
    float2 E = rowE2[m0 + row];
    EA[rr] = E.x; EB[rr] = E.y;
    adst[rr] = row*128 + axor;
    bmp[rr] = bm8 + (size_t)(m0+row)*1024 + (kz0>>3) + akc;
  }
  const uint32* uwp = uwb + kz0 + akc*8;

  f32x4 acc[4][4];
  #pragma unroll
  for (int i=0;i<4;++i)
    #pragma unroll
    for (int j=0;j<4;++j) acc[i][j] = (f32x4){0.f,0.f,0.f,0.f};

  // prefetch A-inputs for t=0
  uint4 nuq0 = *(const uint4*)(uwp);
  uint4 nuq1 = *(const uint4*)(uwp + 4);
  uchar nmb[4];
  #pragma unroll
  for (int rr=0;rr<4;++rr) nmb[rr] = bmp[rr][0];

  const int wr = wid>>1, wc = wid&1;

  for (int t=0;t<ksteps;++t){
    const int k0 = t*64;
    // issue B loads for step t (prior reads of Btm completed by loop-end barrier)
    #pragma unroll
    for (int r=0;r<4;++r) gload16(gB + r*(32*NN) + k0, ldsB + r*4096);
    // rotate A-inputs; prefetch t+1
    const uint4 uq0 = nuq0, uq1 = nuq1;
    uchar mb[4];
    #pragma unroll
    for (int rr=0;rr<4;++rr) mb[rr] = nmb[rr];
    if (t+1 < ksteps){
      nuq0 = *(const uint4*)(uwp + (t+1)*64);
      nuq1 = *(const uint4*)(uwp + (t+1)*64 + 4);
      #pragma unroll
      for (int rr=0;rr<4;++rr) nmb[rr] = bmp[rr][(t+1)*8];
    }
    // A-gen -> LDS
    {
      const uint32 qa[8] = {uq0.x,uq0.y,uq0.z,uq0.w,uq1.x,uq1.y,uq1.z,uq1.w};
      float uu[8], ww[8];
      #pragma unroll
      for (int e=0;e<8;++e){
        uu[e] = __uint_as_float(qa[e]<<16);
        ww[e] = __uint_as_float(qa[e]&0xffff0000u);
      }
      #pragma unroll
      for (int rr=0;rr<4;++rr){
        short av[8];
        #pragma unroll
        for (int e=0;e<8;++e){
          const float v = fmaxf(EA[rr]*uu[e], EB[rr]*ww[e]);
          av[e] = f2bf(((mb[rr]>>e)&1) ? v : 0.0f);
        }
        *(uint4*)((char*)At + adst[rr]) = *(const uint4*)av;
      }
    }
    __syncthreads();   // drains vmcnt (B tile) + lgkm (A tile)
    // MFMA: 4x4 fragments, wave (wr,wc) owns rows wr*64.., cols wc*64..
    #pragma unroll
    for (int ks=0;ks<2;++ks){
      const int kc = ks*4 + (lane>>4);
      bf16x8 af[4];
      #pragma unroll
      for (int mf=0;mf<4;++mf){
        const int r = wr*64 + mf*16 + (lane&15);
        af[mf] = *(const bf16x8*)((char*)At + r*128 + ((kc^(r&7))*16));
      }
      #pragma unroll
      for (int nf=0;nf<4;++nf){
        const int c = wc*64 + nf*16 + (lane&15);
        const bf16x8 bv = *(const bf16x8*)((char*)Btm + c*128 + ((kc^(c&7))*16));
        #pragma unroll
        for (int mf=0;mf<4;++mf)
          acc[mf][nf] = __builtin_amdgcn_mfma_f32_16x16x32_bf16(af[mf], bv, acc[mf][nf],0,0,0);
      }
    }
    __syncthreads();   // Btm/At reads done before next overwrite
  }
  // epilogue: raw f32 partial store (no ELU here)
  #pragma unroll
  for (int mf=0;mf<4;++mf)
    #pragma unroll
    for (int nf=0;nf<4;++nf){
      const int col = n0 + wc*64 + nf*16 + (lane&15);
      #pragma unroll
      for (int q=0;q<4;++q){
        const int r = m0 + wr*64 + mf*16 + (lane>>4)*4 + q;
        outP[(size_t)r*F + col] = acc[mf][nf][q];
      }
    }
}

// ---------- reduce: out = elu(P0 [+ P1]) ----------
__global__ __launch_bounds__(256) void k_red(const float* __restrict__ P1,
    float* __restrict__ out, int two){
  const size_t i = ((size_t)blockIdx.x*256 + threadIdx.x)*4;
  float4 a = *(float4*)(out+i);
  if (two){
    const float4 b = *(const float4*)(P1+i);
    a.x+=b.x; a.y+=b.y; a.z+=b.z; a.w+=b.w;
  }
  a.x = (a.x>0.f)?a.x:expm1f(a.x);
  a.y = (a.y>0.f)?a.y:expm1f(a.y);
  a.z = (a.z>0.f)?a.z:expm1f(a.z);
  a.w = (a.w>0.f)?a.w:expm1f(a.w);
  *(float4*)(out+i) = a;
}

extern "C" void kernel_launch(void* const* d_in, const int* in_sizes, int n_in,
                              void* d_out, int out_size, void* d_ws, size_t ws_size,
                              hipStream_t stream) {
  (void)in_sizes; (void)n_in; (void)out_size;
  const int*   adj  = (const int*)d_in[0];
  const float* X    = (const float*)d_in[1];
  const float* W    = (const float*)d_in[2];
  const float* attn = (const float*)d_in[3];
  float* out = (float*)d_out;
  char* ws = (char*)d_ws;
  // layout: HT | bm32 | small tables | P1 (aliases Xb,WbT which die after k_gemm1)
  short*  HT   = (short*)(ws);                        // 8 MB
  uint32* bm32 = (uint32*)(ws + 8388608);             // 8 MB
  float*  s1L  = (float*)(ws + 16777216);             // 32 KB
  float*  uwf  = (float*)(ws + 16809984);             // 64 KB
  uint32* uwb  = (uint32*)(ws + 16875520);            // 32 KB
  float2* rowE2= (float2*)(ws + 16908288);            // 64 KB
  float*  wa   = (float*)(ws + 16973824);             // 4 KB
  float*  P1   = (float*)(ws + 16978944);             // 16.78 MB (aliased below)
  short*  Xb   = (short*)(ws + 16978944);             // 8 MB   (dead after k_gemm1)
  short*  WbT  = (short*)(ws + 25367552);             // 0.5 MB (dead after k_gemm1)
  const size_t NEED2 = 16978944ull + 16777216ull;     // 33.76 MB for split-K x2
  const int KS = (ws_size >= NEED2) ? 2 : 1;
  const int ksteps = 128/KS;

  k_wa   <<<dim3(256),   dim3(256), 0, stream>>>(W, attn, wa);
  k_tw   <<<dim3(8,8),   dim3(256), 0, stream>>>(W, WbT);
  k_prep <<<dim3(2048),  dim3(256), 0, stream>>>(X, wa, Xb, s1L, (float2*)uwf, uwb);
  k_gemm1<<<dim3(64,4),  dim3(256), 0, stream>>>(Xb, WbT, HT);
  k_stats<<<dim3(8192),  dim3(256), 0, stream>>>(adj, s1L, uwf, bm32, rowE2);
  k_pv   <<<dim3(64,4,KS), dim3(256), 0, stream>>>(HT, (const uchar*)bm32, rowE2, uwb, out, P1, ksteps);
  k_red  <<<dim3(4096),  dim3(256), 0, stream>>>(P1, out, KS-1);
}